// Round 2
// baseline (213.615 us; speedup 1.0000x reference)
//
#include <hip/hip_runtime.h>
#include <math.h>

// B=8, N=32, M=64, D=128, OUT=128, K=3, P=N*N=1024, r=512
#define EPS 1e-5f

// stats layout (floats) in ws[0..1023]:
//  [0..127]   sum_sc   [128..255] sq_sc
//  [256..319] sum1     [320..383] sq1
//  [384..447] sum2     [448..511] sq2
//  [512..543] sum3     [544..575] sq3

__device__ __forceinline__ void fma4(float4& a, float s, const float4& v) {
    a.x += s * v.x; a.y += s * v.y; a.z += s * v.z; a.w += s * v.w;
}

// 8ch x 8d x 2m FMA step: W0 = ch..ch+3, W1 = ch+4..ch+7 at one m.
#define FMA_STEP(W0, W1, X0, X1) \
    fma4(acc[0][0], W0.x, X0); fma4(acc[0][1], W0.x, X1); \
    fma4(acc[1][0], W0.y, X0); fma4(acc[1][1], W0.y, X1); \
    fma4(acc[2][0], W0.z, X0); fma4(acc[2][1], W0.z, X1); \
    fma4(acc[3][0], W0.w, X0); fma4(acc[3][1], W0.w, X1); \
    fma4(acc[4][0], W1.x, X0); fma4(acc[4][1], W1.x, X1); \
    fma4(acc[5][0], W1.y, X0); fma4(acc[5][1], W1.y, X1); \
    fma4(acc[6][0], W1.z, X0); fma4(acc[6][1], W1.z, X1); \
    fma4(acc[7][0], W1.w, X0); fma4(acc[7][1], W1.w, X1);

// ---------------------------------------------------------------------------
// K1 v4: t_sc[b,o,n,d] = sum_m W_sc[o,m] x[b,n,m,d]; t_l1 likewise for W_l1.
// grid (4, 256): x = ch-group of 64 concat channels (g<3), y = (b,n).
// g==3: C1 precompute for the rank-2 FC1 collapse.
// Core: s_x rows padded 144 (16B per 32 floats) -> 2-way banks on x-reads;
// W staged via coalesced row loads + b64 transpose writes; per-lane 8ch x 8d;
// 2-way m-split across wave pairs with b64 LDS reduce. 54272 B LDS -> 3 blk/CU.
__global__ __launch_bounds__(256, 3) void k1_matmul_stats(
    const float* __restrict__ x, const float* __restrict__ Wsc,
    const float* __restrict__ Wl1, const float* __restrict__ Wfc1,
    float* __restrict__ t_sc, float* __restrict__ t_l1,
    float* __restrict__ C1, float* __restrict__ stats)
{
    int g  = blockIdx.x;       // 0..3
    int bn = blockIdx.y;       // 0..255
    __shared__ __align__(16) float s_x[64 * 144];   // [m][d swizzled]
    __shared__ __align__(16) float s_wT[64 * 68];   // [m][cc_local], pad 68
    int t = threadIdx.x;

    if (g == 3) {
        // C1 precompute: block handles rows r = bn*2, bn*2+1 of W_fc1.
        //   C1[r,k] = (sum_j W1[r,k*32+j] + 2*sum_i W1[r,i*32+k] - W1[r,k*33]) / 256
#pragma unroll
        for (int rr = 0; rr < 2; rr++) {
            int r = bn * 2 + rr;
            *(float4*)(s_x + t * 4) =
                *(const float4*)(Wfc1 + (size_t)r * 1024 + t * 4);
            __syncthreads();
            if (t < 32) {
                float rs = 0.f, cs = 0.f;
#pragma unroll
                for (int j = 0; j < 32; j++) {
                    rs += s_x[t * 32 + j];      // row-block sum (S_i coeff)
                    cs += s_x[j * 32 + t];      // col sum (S_j coeff)
                }
                C1[r * 32 + t] = (rs + 2.f * cs - s_x[t * 33]) * (1.0f / 256.0f);
            }
            __syncthreads();
        }
        return;
    }

    int b = bn >> 5, n = bn & 31;
    // stage x: element d of row m at m*144 + d + (d>>5)*4
    const float4* xg = (const float4*)(x + (size_t)bn * 8192);
    for (int i = t; i < 2048; i += 256) {
        int row = i >> 5, j = i & 31;
        *(float4*)(s_x + row * 144 + j * 4 + ((j >> 3) << 2)) = xg[i];
    }
    // stage W: coalesced row reads (lane = m), b64 transpose writes [m][o]
    const float* wbase = (g < 2) ? (Wsc + (size_t)g * 4096) : Wl1;
    {
        int m = t & 63, tg = t >> 6;        // tg uniform per wave
        float val[16];
#pragma unroll
        for (int o = 0; o < 16; o++)
            val[o] = wbase[(size_t)(tg * 16 + o) * 64 + m];
        float* wr = s_wT + m * 68 + tg * 16;
#pragma unroll
        for (int q = 0; q < 8; q++)
            *(float2*)(wr + 2 * q) = make_float2(val[2 * q], val[2 * q + 1]);
    }
    __syncthreads();

    int w = t >> 6, lane = t & 63;
    int mh = w >> 1, p = w & 1;            // m-half, ch-half
    int dl = lane & 15, cg = lane >> 4;
    int d0 = dl * 8;
    int ch = p * 32 + cg * 8;              // local cc base, 8 channels
    int xoff = d0 + ((dl >> 2) << 2);      // swizzled float offset

    float4 acc[8][2];
#pragma unroll
    for (int i = 0; i < 8; i++) { acc[i][0] = make_float4(0,0,0,0); acc[i][1] = make_float4(0,0,0,0); }

    int m0 = mh * 32;
    for (int m = m0; m < m0 + 32; m += 2) {
        const float* xr0 = s_x + m * 144 + xoff;
        const float* wr0 = s_wT + m * 68 + ch;
        float4 xA0 = *(const float4*)(xr0);
        float4 xA1 = *(const float4*)(xr0 + 4);
        float4 xB0 = *(const float4*)(xr0 + 144);
        float4 xB1 = *(const float4*)(xr0 + 148);
        float4 wA0 = *(const float4*)(wr0);
        float4 wA1 = *(const float4*)(wr0 + 4);
        float4 wB0 = *(const float4*)(wr0 + 68);
        float4 wB1 = *(const float4*)(wr0 + 72);
        FMA_STEP(wA0, wA1, xA0, xA1)
        FMA_STEP(wB0, wB1, xB0, xB1)
    }

    // cross-wave m-reduce: waves mh==1 dump partials, mh==0 add.
    __syncthreads();
    float* s_red = s_x;                    // reuse, 128 rows x 66 floats
    if (mh == 1) {
        float* row = s_red + (p * 64 + lane) * 66;
#pragma unroll
        for (int i = 0; i < 8; i++) {
            *(float2*)(row + i * 8 + 0) = make_float2(acc[i][0].x, acc[i][0].y);
            *(float2*)(row + i * 8 + 2) = make_float2(acc[i][0].z, acc[i][0].w);
            *(float2*)(row + i * 8 + 4) = make_float2(acc[i][1].x, acc[i][1].y);
            *(float2*)(row + i * 8 + 6) = make_float2(acc[i][1].z, acc[i][1].w);
        }
    }
    __syncthreads();
    if (mh == 0) {
        const float* row = s_red + (p * 64 + lane) * 66;
#pragma unroll
        for (int i = 0; i < 8; i++) {
            float2 p0 = *(const float2*)(row + i * 8 + 0);
            float2 p1 = *(const float2*)(row + i * 8 + 2);
            float2 p2 = *(const float2*)(row + i * 8 + 4);
            float2 p3 = *(const float2*)(row + i * 8 + 6);
            acc[i][0].x += p0.x; acc[i][0].y += p0.y;
            acc[i][0].z += p1.x; acc[i][0].w += p1.y;
            acc[i][1].x += p2.x; acc[i][1].y += p2.y;
            acc[i][1].z += p3.x; acc[i][1].w += p3.y;
        }
#pragma unroll
        for (int i = 0; i < 8; i++) {
            int cc = g * 64 + ch + i;
            float4 v0 = acc[i][0], v1 = acc[i][1];
            float* dst;
            if (cc < 128) dst = t_sc + (((size_t)(b * 128 + cc)) * 32 + n) * 128 + d0;
            else          dst = t_l1 + (((size_t)(b * 64 + (cc - 128))) * 32 + n) * 128 + d0;
            *(float4*)dst = v0;
            *(float4*)(dst + 4) = v1;
            float s = v0.x + v0.y + v0.z + v0.w + v1.x + v1.y + v1.z + v1.w;
            float q = v0.x*v0.x + v0.y*v0.y + v0.z*v0.z + v0.w*v0.w
                    + v1.x*v1.x + v1.y*v1.y + v1.z*v1.z + v1.w*v1.w;
#pragma unroll
            for (int off = 8; off > 0; off >>= 1) {
                s += __shfl_down(s, off, 16);
                q += __shfl_down(q, off, 16);
            }
            if (dl == 0) {
                if (cc < 128) {
                    atomicAdd(&stats[cc], s);
                    atomicAdd(&stats[cc + 128], q);
                } else {
                    atomicAdd(&stats[256 + (cc - 128)], s);
                    atomicAdd(&stats[320 + (cc - 128)], q);
                }
            }
        }
    }
}

// ---------------------------------------------------------------------------
// K2 v4: per (b,m): y = bn1(t_l1); row sums S_i; dot/eq over pairs;
// maskbits = (num>0); store y. FC1 fused via rank-2 collapse + anomalies.
// y_s rows at r*132 + (r>>2)*8 -> pair-loop b-reads are 2-way (was 4-way).
__device__ __forceinline__ int yb(int r) { return r * 132 + ((r >> 2) << 3); }

__global__ __launch_bounds__(256) void k2_attn_prep(
    const float* __restrict__ t_l1, const float* __restrict__ g1,
    const float* __restrict__ b1, const float* __restrict__ stats,
    const float* __restrict__ Wfc1, const float* __restrict__ C1,
    float* __restrict__ y_g, float* __restrict__ H,
    unsigned int* __restrict__ maskbits)
{
    int bm = blockIdx.x;
    int t  = threadIdx.x;
    __shared__ __align__(16) float y_s[4288];
    __shared__ float S_s[32];
    __shared__ unsigned int m_s[32];
    __shared__ int anom_cnt;
    __shared__ int anom_p[64];
    __shared__ float anom_v[64];
    int m = bm & 63;
    float mean = stats[256 + m] * (1.0f / 32768.0f);
    float var  = stats[320 + m] * (1.0f / 32768.0f) - mean * mean;
    float a = g1[m] * rsqrtf(var + EPS);
    float c = b1[m] - a * mean;

    if (t == 0) anom_cnt = 0;
    if (t < 32) m_s[t] = 0u;
    const float4* src = (const float4*)(t_l1 + (size_t)bm * 4096);
    for (int i = t; i < 1024; i += 256) {
        float4 v = src[i];
        v.x = a * v.x + c; v.y = a * v.y + c; v.z = a * v.z + c; v.w = a * v.w + c;
        int row = i >> 5, col = (i & 31) * 4;
        *(float4*)(y_s + yb(row) + col) = v;
    }
    __syncthreads();

    {   // row sums
        int r = t >> 3, j = t & 7;
        float s = 0.f;
        const float* yr = y_s + yb(r) + j * 16;
#pragma unroll
        for (int dd = 0; dd < 16; dd++) s += yr[dd];
#pragma unroll
        for (int off = 4; off > 0; off >>= 1) s += __shfl_down(s, off, 8);
        if (j == 0) S_s[r] = s;
    }
    __syncthreads();

    int i = t >> 3, j0 = (t & 7) * 4;
    float dot[4] = {0.f, 0.f, 0.f, 0.f};
    float eqs[4] = {0.f, 0.f, 0.f, 0.f};
    const float* yi = y_s + yb(i);
    const float* yj[4] = { y_s + yb(j0), y_s + yb(j0 + 1),
                           y_s + yb(j0 + 2), y_s + yb(j0 + 3) };
    for (int dq = 0; dq < 32; dq++) {
        float4 a4 = *(const float4*)(yi + dq * 4);
#pragma unroll
        for (int q = 0; q < 4; q++) {
            float4 b4 = *(const float4*)(yj[q] + dq * 4);
            dot[q] += a4.x * b4.x + a4.y * b4.y + a4.z * b4.z + a4.w * b4.w;
            eqs[q] += (a4.x == b4.x ? b4.x : 0.f) + (a4.y == b4.y ? b4.y : 0.f)
                    + (a4.z == b4.z ? b4.z : 0.f) + (a4.w == b4.w ? b4.w : 0.f);
        }
    }
    float Si = S_s[i];
    unsigned int bits = 0u;
#pragma unroll
    for (int q = 0; q < 4; q++) {
        int j = j0 + q;
        float Sj = S_s[j];
        float num = dot[q] - Si * Sj * (1.0f / 128.0f);
        if (num > 0.f) bits |= (1u << j);
        // exact-collision correction term for the FC1 collapse (diag is in C1)
        if (j != i && eqs[q] != 0.f) {
            int idx = atomicAdd(&anom_cnt, 1);
            if (idx < 64) {
                anom_p[idx] = i * 32 + j;
                anom_v[idx] = eqs[q] * (1.0f / 256.0f);
            }
        }
    }
    atomicOr(&m_s[i], bits);
    __syncthreads();
    if (t < 32) maskbits[bm * 32 + t] = m_s[t];

    // fused FC1: h[bm, r] = relu( sum_k C1[r,k]*S_k - sum_anom W1[r,p]*v )
    int cnt = anom_cnt; if (cnt > 64) cnt = 64;
#pragma unroll
    for (int rr = 0; rr < 2; rr++) {
        int r = t * 2 + rr;
        const float4* c1r = (const float4*)(C1 + r * 32);
        float acc = 0.f;
#pragma unroll
        for (int kk = 0; kk < 8; kk++) {
            float4 cv = c1r[kk];
            acc += cv.x * S_s[kk * 4 + 0] + cv.y * S_s[kk * 4 + 1]
                 + cv.z * S_s[kk * 4 + 2] + cv.w * S_s[kk * 4 + 3];
        }
        for (int a2 = 0; a2 < cnt; a2++)
            acc -= Wfc1[(size_t)r * 1024 + anom_p[a2]] * anom_v[a2];
        H[(size_t)bm * 512 + r] = fmaxf(acc, 0.f);
    }

    float4* yd = (float4*)(y_g + (size_t)bm * 4096);
    for (int idx = t; idx < 1024; idx += 256) {
        int row = idx >> 5, col = (idx & 31) * 4;
        yd[idx] = *(const float4*)(y_s + yb(row) + col);
    }
}

// ---------------------------------------------------------------------------
// K3: C[r,c] = epi( sum_k A[r,k] * Bm[c,k] ). 32x32 tile per block,
// in-block split-K: 4 waves, each owns K/4 via wave-private LDS slabs.
// MODE 1: sigmoid (FC2). (FC1 is collapsed into K2.)
template<int KDIM, int MODE>
__global__ __launch_bounds__(256) void k3_gemm(
    const float* __restrict__ A, const float* __restrict__ Bm,
    float* __restrict__ C, int NC)
{
    __shared__ __align__(16) float lds[4 * 2304];   // per wave: As 32x36, Bs 32x36
    int t = threadIdx.x;
    int w = t >> 6, l = t & 63;
    int ct = blockIdx.x, rt = blockIdx.y;
    int row0 = rt * 32, col0 = ct * 32;
    float* As = lds + w * 2304;
    float* Bs = As + 1152;
    int rg = l >> 3;           // 0..7 : rows rg*4.., also staging row group
    int cg = l & 7;            // 0..7 : cols cg*4..
    int kq = (l & 7) * 4;      // staging k-offset within slab
    constexpr int SLABS = KDIM / 128;

    float4 acc[4];
#pragma unroll
    for (int ii = 0; ii < 4; ii++) acc[ii] = make_float4(0,0,0,0);

    float4 av[4], bv[4], av2[4], bv2[4];
    int k0 = w * 32;
#pragma unroll
    for (int rr = 0; rr < 4; rr++) {
        int r = rg + rr * 8;
        av[rr] = *(const float4*)(A  + (size_t)(row0 + r) * KDIM + k0 + kq);
        bv[rr] = *(const float4*)(Bm + (size_t)(col0 + r) * KDIM + k0 + kq);
    }

    for (int s = 0; s < SLABS; s++) {
#pragma unroll
        for (int rr = 0; rr < 4; rr++) {
            int r = rg + rr * 8;
            As[(kq + 0) * 36 + r] = av[rr].x; As[(kq + 1) * 36 + r] = av[rr].y;
            As[(kq + 2) * 36 + r] = av[rr].z; As[(kq + 3) * 36 + r] = av[rr].w;
            Bs[(kq + 0) * 36 + r] = bv[rr].x; Bs[(kq + 1) * 36 + r] = bv[rr].y;
            Bs[(kq + 2) * 36 + r] = bv[rr].z; Bs[(kq + 3) * 36 + r] = bv[rr].w;
        }
        if (s + 1 < SLABS) {
            int kn = (4 * (s + 1) + w) * 32;
#pragma unroll
            for (int rr = 0; rr < 4; rr++) {
                int r = rg + rr * 8;
                av2[rr] = *(const float4*)(A  + (size_t)(row0 + r) * KDIM + kn + kq);
                bv2[rr] = *(const float4*)(Bm + (size_t)(col0 + r) * KDIM + kn + kq);
            }
        }
#pragma unroll
        for (int k = 0; k < 32; k++) {
            float4 a = *(const float4*)(As + k * 36 + rg * 4);
            float4 b = *(const float4*)(Bs + k * 36 + cg * 4);
            fma4(acc[0], a.x, b);
            fma4(acc[1], a.y, b);
            fma4(acc[2], a.z, b);
            fma4(acc[3], a.w, b);
        }
#pragma unroll
        for (int rr = 0; rr < 4; rr++) { av[rr] = av2[rr]; bv[rr] = bv2[rr]; }
    }

    __syncthreads();
    float* red = lds;          // 4 x 1024 overlay
#pragma unroll
    for (int ii = 0; ii < 4; ii++)
        *(float4*)(red + w * 1024 + (rg * 4 + ii) * 32 + cg * 4) = acc[ii];
    __syncthreads();

    int r = t >> 3, c4 = (t & 7) * 4;
    float4 s0 = *(const float4*)(red + r * 32 + c4);
    float4 s1 = *(const float4*)(red + 1024 + r * 32 + c4);
    float4 s2 = *(const float4*)(red + 2048 + r * 32 + c4);
    float4 s3 = *(const float4*)(red + 3072 + r * 32 + c4);
    float4 v;
    v.x = s0.x + s1.x + s2.x + s3.x;
    v.y = s0.y + s1.y + s2.y + s3.y;
    v.z = s0.z + s1.z + s2.z + s3.z;
    v.w = s0.w + s1.w + s2.w + s3.w;
    if (MODE == 0) {
        v.x = fmaxf(v.x, 0.f); v.y = fmaxf(v.y, 0.f);
        v.z = fmaxf(v.z, 0.f); v.w = fmaxf(v.w, 0.f);
    } else {
        v.x = 1.0f / (1.0f + expf(-v.x)); v.y = 1.0f / (1.0f + expf(-v.y));
        v.z = 1.0f / (1.0f + expf(-v.z)); v.w = 1.0f / (1.0f + expf(-v.w));
    }
    *(float4*)(C + (size_t)(row0 + r) * NC + col0 + c4) = v;
}

// ---------------------------------------------------------------------------
// K4: per (b,m): att = softmax_j( mask ? e2 : -1e12 ); out = att @ y; stats2.
// j-outer MV loop: each y[j] float4 read once.
__global__ __launch_bounds__(256) void k4_attn_apply(
    const float* __restrict__ E2, const unsigned int* __restrict__ maskbits,
    const float* __restrict__ y_g, float* __restrict__ att_out,
    float* __restrict__ stats)
{
    int bm = blockIdx.x;
    int t  = threadIdx.x;
    __shared__ __align__(16) float att_s[32 * 33];
    __shared__ __align__(16) float y_sh[32 * 128];
    __shared__ float redS[4], redQ[4];

    const float4* ysrc = (const float4*)(y_g + (size_t)bm * 4096);
    float4* yds = (float4*)y_sh;
    for (int i = t; i < 1024; i += 256) yds[i] = ysrc[i];

    {
        int r = t >> 3, j0 = (t & 7) * 4;
        unsigned int mk = maskbits[bm * 32 + r];
        float4 e4 = *(const float4*)(E2 + (size_t)bm * 1024 + r * 32 + j0);
        float v0 = ((mk >> (j0 + 0)) & 1u) ? e4.x : -1e12f;
        float v1 = ((mk >> (j0 + 1)) & 1u) ? e4.y : -1e12f;
        float v2 = ((mk >> (j0 + 2)) & 1u) ? e4.z : -1e12f;
        float v3 = ((mk >> (j0 + 3)) & 1u) ? e4.w : -1e12f;
        float mx = fmaxf(fmaxf(v0, v1), fmaxf(v2, v3));
#pragma unroll
        for (int off = 1; off < 8; off <<= 1) mx = fmaxf(mx, __shfl_xor(mx, off, 8));
        float e0 = __expf(v0 - mx), e1 = __expf(v1 - mx);
        float e2 = __expf(v2 - mx), e3 = __expf(v3 - mx);
        float s = e0 + e1 + e2 + e3;
#pragma unroll
        for (int off = 1; off < 8; off <<= 1) s += __shfl_xor(s, off, 8);
        float inv = 1.0f / s;
        att_s[r * 33 + j0 + 0] = e0 * inv;
        att_s[r * 33 + j0 + 1] = e1 * inv;
        att_s[r * 33 + j0 + 2] = e2 * inv;
        att_s[r * 33 + j0 + 3] = e3 * inv;
    }
    __syncthreads();

    int tx = t & 31, ty = t >> 5;
    int dq = tx * 4;
    int i0 = ty * 4;
    float4 acc0 = make_float4(0,0,0,0), acc1 = make_float4(0,0,0,0);
    float4 acc2 = make_float4(0,0,0,0), acc3 = make_float4(0,0,0,0);
    for (int j = 0; j < 32; j++) {
        float4 yv = *(const float4*)(y_sh + j * 128 + dq);
        float w0 = att_s[(i0 + 0) * 33 + j];
        float w1 = att_s[(i0 + 1) * 33 + j];
        float w2 = att_s[(i0 + 2) * 33 + j];
        float w3 = att_s[(i0 + 3) * 33 + j];
        fma4(acc0, w0, yv);
        fma4(acc1, w1, yv);
        fma4(acc2, w2, yv);
        fma4(acc3, w3, yv);
    }
    float ssum = 0.f, sq = 0.f;
    float4 accs[4] = {acc0, acc1, acc2, acc3};
#pragma unroll
    for (int ii = 0; ii < 4; ii++) {
        float4 acc = accs[ii];
        *(float4*)(att_out + (size_t)bm * 4096 + (i0 + ii) * 128 + dq) = acc;
        ssum += acc.x + acc.y + acc.z + acc.w;
        sq   += acc.x * acc.x + acc.y * acc.y + acc.z * acc.z + acc.w * acc.w;
    }
#pragma unroll
    for (int off = 32; off > 0; off >>= 1) {
        ssum += __shfl_down(ssum, off, 64);
        sq   += __shfl_down(sq, off, 64);
    }
    int wave = t >> 6, lane = t & 63;
    if (lane == 0) { redS[wave] = ssum; redQ[wave] = sq; }
    __syncthreads();
    if (t == 0) {
        float S = redS[0] + redS[1] + redS[2] + redS[3];
        float Q = redQ[0] + redQ[1] + redQ[2] + redQ[3];
        int m = bm & 63;
        atomicAdd(&stats[384 + m], S);
        atomicAdd(&stats[448 + m], Q);
    }
}

// ---------------------------------------------------------------------------
// K5: per (b,n): z = relu(bn2(att_out)); 3x3 depthwise conv; stats3.
__global__ __launch_bounds__(256) void k5_conv(
    const float* __restrict__ att_out, const float* __restrict__ Wdw,
    const float* __restrict__ g2, const float* __restrict__ b2,
    float* __restrict__ stats, float* __restrict__ v_g)
{
    int bn = blockIdx.x;
    int b = bn >> 5, n = bn & 31;
    int t = threadIdx.x;
    __shared__ __align__(16) float z_s[66 * 130];
    __shared__ float a2_s[64], c2_s[64];
    __shared__ float redS[4], redQ[4];

    if (t < 64) {
        float mean = stats[384 + t] * (1.0f / 32768.0f);
        float var  = stats[448 + t] * (1.0f / 32768.0f) - mean * mean;
        float a = g2[t] * rsqrtf(var + EPS);
        a2_s[t] = a; c2_s[t] = b2[t] - a * mean;
    }
    for (int i = t; i < 66 * 130; i += 256) z_s[i] = 0.f;
    __syncthreads();

    for (int i = t; i < 2048; i += 256) {
        int m = i >> 5, c4 = (i & 31) * 4;
        float4 vv = *(const float4*)(att_out + (((size_t)(b * 64 + m)) * 32 + n) * 128 + c4);
        float a = a2_s[m], c = c2_s[m];
        float* dst = z_s + (m + 1) * 130 + c4 + 1;
        dst[0] = fmaxf(a * vv.x + c, 0.f);
        dst[1] = fmaxf(a * vv.y + c, 0.f);
        dst[2] = fmaxf(a * vv.z + c, 0.f);
        dst[3] = fmaxf(a * vv.w + c, 0.f);
    }
    float w[9];
#pragma unroll
    for (int i = 0; i < 9; i++) w[i] = Wdw[n * 9 + i];
    __syncthreads();

    int tx = t & 31, ty = t >> 5;
    int d0 = tx * 4;
    float ssum = 0.f, sq = 0.f;
#pragma unroll
    for (int rr = 0; rr < 8; rr++) {
        int h = ty * 8 + rr;
        float o0 = 0.f, o1 = 0.f, o2 = 0.f, o3 = 0.f;
#pragma unroll
        for (int dh = 0; dh < 3; dh++) {
            const float* zr = z_s + (h + dh) * 130 + d0;
#pragma unroll
            for (int dw = 0; dw < 3; dw++) {
                float wv = w[dh * 3 + dw];
                o0 += wv * zr[dw + 0];
                o1 += wv * zr[dw + 1];
                o2 += wv * zr[dw + 2];
                o3 += wv * zr[dw + 3];
            }
        }
        *(float4*)(v_g + ((size_t)bn * 64 + h) * 128 + d0) = make_float4(o0, o1, o2, o3);
        ssum += o0 + o1 + o2 + o3;
        sq   += o0 * o0 + o1 * o1 + o2 * o2 + o3 * o3;
    }
#pragma unroll
    for (int off = 32; off > 0; off >>= 1) {
        ssum += __shfl_down(ssum, off, 64);
        sq   += __shfl_down(sq, off, 64);
    }
    int wave = t >> 6, lane = t & 63;
    if (lane == 0) { redS[wave] = ssum; redQ[wave] = sq; }
    __syncthreads();
    if (t == 0) {
        atomicAdd(&stats[512 + n], redS[0] + redS[1] + redS[2] + redS[3]);
        atomicAdd(&stats[544 + n], redQ[0] + redQ[1] + redQ[2] + redQ[3]);
    }
}

// ---------------------------------------------------------------------------
// K6 v3: out[b,n,o,d] = sum_m Wl3[o,m]*relu(bn3(v[b,n,m,d])) + bn_sc(t_sc)
// grid (2, 256): x = o-half of 64, y = (b,n). Same core as K1 v4.
__global__ __launch_bounds__(256, 3) void k6_final(
    const float* __restrict__ v_g, const float* __restrict__ t_sc,
    const float* __restrict__ Wl3, const float* __restrict__ g3,
    const float* __restrict__ b3, const float* __restrict__ gsc,
    const float* __restrict__ bsc, const float* __restrict__ stats,
    float* __restrict__ outp)
{
    int oh = blockIdx.x;       // 0/1
    int bn = blockIdx.y;
    int b = bn >> 5, n = bn & 31;
    int t = threadIdx.x;
    __shared__ __align__(16) float z_s[64 * 144];   // [m][d swizzled] relu(bn3(v))
    __shared__ __align__(16) float s_wT[64 * 68];   // [m][o_local]

    float mean3 = stats[512 + n] * (1.0f / 65536.0f);
    float var3  = stats[544 + n] * (1.0f / 65536.0f) - mean3 * mean3;
    float a3 = g3[n] * rsqrtf(var3 + EPS);
    float c3 = b3[n] - a3 * mean3;

    const float4* vsrc = (const float4*)(v_g + (size_t)bn * 8192);
    for (int i = t; i < 2048; i += 256) {
        float4 vv = vsrc[i];
        float4 r;
        r.x = fmaxf(a3 * vv.x + c3, 0.f);
        r.y = fmaxf(a3 * vv.y + c3, 0.f);
        r.z = fmaxf(a3 * vv.z + c3, 0.f);
        r.w = fmaxf(a3 * vv.w + c3, 0.f);
        int row = i >> 5, j = i & 31;
        *(float4*)(z_s + row * 144 + j * 4 + ((j >> 3) << 2)) = r;
    }
    const float* wbase = Wl3 + (size_t)oh * 4096;
    {
        int m = t & 63, tg = t >> 6;
        float val[16];
#pragma unroll
        for (int o = 0; o < 16; o++)
            val[o] = wbase[(size_t)(tg * 16 + o) * 64 + m];
        float* wr = s_wT + m * 68 + tg * 16;
#pragma unroll
        for (int q = 0; q < 8; q++)
            *(float2*)(wr + 2 * q) = make_float2(val[2 * q], val[2 * q + 1]);
    }
    __syncthreads();

    int w = t >> 6, lane = t & 63;
    int mh = w >> 1, p = w & 1;
    int dl = lane & 15, cg = lane >> 4;
    int d0 = dl * 8;
    int ch = p * 32 + cg * 8;
    int xoff = d0 + ((dl >> 2) << 2);

    float4 acc[8][2];
#pragma unroll
    for (int i = 0; i < 8; i++) { acc[i][0] = make_float4(0,0,0,0); acc[i][1] = make_float4(0,0,0,0); }

    int m0 = mh * 32;
    for (int m = m0; m < m0 + 32; m += 2) {
        const float* xr0 = z_s + m * 144 + xoff;
        const float* wr0 = s_wT + m * 68 + ch;
        float4 xA0 = *(const float4*)(xr0);
        float4 xA1 = *(const float4*)(xr0 + 4);
        float4 xB0 = *(const float4*)(xr0 + 144);
        float4 xB1 = *(const float4*)(xr0 + 148);
        float4 wA0 = *(const float4*)(wr0);
        float4 wA1 = *(const float4*)(wr0 + 4);
        float4 wB0 = *(const float4*)(wr0 + 68);
        float4 wB1 = *(const float4*)(wr0 + 72);
        FMA_STEP(wA0, wA1, xA0, xA1)
        FMA_STEP(wB0, wB1, xB0, xB1)
    }

    __syncthreads();
    float* s_red = z_s;
    if (mh == 1) {
        float* row = s_red + (p * 64 + lane) * 66;
#pragma unroll
        for (int i = 0; i < 8; i++) {
            *(float2*)(row + i * 8 + 0) = make_float2(acc[i][0].x, acc[i][0].y);
            *(float2*)(row + i * 8 + 2) = make_float2(acc[i][0].z, acc[i][0].w);
            *(float2*)(row + i * 8 + 4) = make_float2(acc[i][1].x, acc[i][1].y);
            *(float2*)(row + i * 8 + 6) = make_float2(acc[i][1].z, acc[i][1].w);
        }
    }
    __syncthreads();
    if (mh == 0) {
        const float* row = s_red + (p * 64 + lane) * 66;
#pragma unroll
        for (int i = 0; i < 8; i++) {
            float2 p0 = *(const float2*)(row + i * 8 + 0);
            float2 p1 = *(const float2*)(row + i * 8 + 2);
            float2 p2 = *(const float2*)(row + i * 8 + 4);
            float2 p3 = *(const float2*)(row + i * 8 + 6);
            acc[i][0].x += p0.x; acc[i][0].y += p0.y;
            acc[i][0].z += p1.x; acc[i][0].w += p1.y;
            acc[i][1].x += p2.x; acc[i][1].y += p2.y;
            acc[i][1].z += p3.x; acc[i][1].w += p3.y;
        }
#pragma unroll
        for (int i = 0; i < 8; i++) {
            int o = oh * 64 + ch + i;
            float msc = stats[o] * (1.0f / 32768.0f);
            float vsc = stats[128 + o] * (1.0f / 32768.0f) - msc * msc;
            float asc = gsc[o] * rsqrtf(vsc + EPS);
            float csc = bsc[o] - asc * msc;
            const float* ts = t_sc + (((size_t)(b * 128 + o)) * 32 + n) * 128 + d0;
            float4 t0 = *(const float4*)(ts);
            float4 t1 = *(const float4*)(ts + 4);
            float4 o0 = acc[i][0], o1 = acc[i][1];
            o0.x += asc * t0.x + csc; o0.y += asc * t0.y + csc;
            o0.z += asc * t0.z + csc; o0.w += asc * t0.w + csc;
            o1.x += asc * t1.x + csc; o1.y += asc * t1.y + csc;
            o1.z += asc * t1.z + csc; o1.w += asc * t1.w + csc;
            float* dst = outp + (((size_t)(b * 32 + n)) * 128 + o) * 128 + d0;
            *(float4*)dst = o0;
            *(float4*)(dst + 4) = o1;
        }
    }
}

// ---------------------------------------------------------------------------
extern "C" void kernel_launch(void* const* d_in, const int* in_sizes, int n_in,
                              void* d_out, int out_size, void* d_ws, size_t ws_size,
                              hipStream_t stream)
{
    const float* x    = (const float*)d_in[0];
    const float* Wsc  = (const float*)d_in[1];
    const float* gsc  = (const float*)d_in[2];
    const float* bsc  = (const float*)d_in[3];
    const float* Wl1  = (const float*)d_in[4];
    const float* g1   = (const float*)d_in[5];
    const float* b1   = (const float*)d_in[6];
    const float* Wfc1 = (const float*)d_in[7];
    const float* Wfc2 = (const float*)d_in[8];
    const float* g2   = (const float*)d_in[9];
    const float* b2   = (const float*)d_in[10];
    const float* Wdw  = (const float*)d_in[11];
    const float* g3   = (const float*)d_in[12];
    const float* b3   = (const float*)d_in[13];
    const float* Wl3  = (const float*)d_in[14];
    float* outp = (float*)d_out;

    float* ws = (float*)d_ws;
    float* stats = ws;                          // 1024
    float* t_sc  = ws + 1024;                   // 4194304
    float* t_l1  = t_sc + 4194304;              // 2097152 (reused as att_out)
    float* y_g   = t_l1 + 2097152;              // 2097152 (reused as conv out)
    float* C1    = y_g + 2097152;               // 16384 (FC1 collapse matrix)
    float* H     = C1 + 16384;                  // 262144
    float* E2    = H + 262144;                  // 524288
    unsigned int* maskb = (unsigned int*)(E2 + 524288);  // 16384 u32

    (void)hipMemsetAsync(stats, 0, 1024 * sizeof(float), stream);

    k1_matmul_stats<<<dim3(4, 256), 256, 0, stream>>>(x, Wsc, Wl1, Wfc1, t_sc, t_l1, C1, stats);
    k2_attn_prep<<<512, 256, 0, stream>>>(t_l1, g1, b1, stats, Wfc1, C1, y_g, H, maskb);
    k3_gemm<512, 1><<<dim3(32, 16), 256, 0, stream>>>(H, Wfc2, E2, 1024);
    k4_attn_apply<<<512, 256, 0, stream>>>(E2, maskb, y_g, t_l1, stats);
    k5_conv<<<256, 256, 0, stream>>>(t_l1, Wdw, g2, b2, stats, y_g);
    k6_final<<<dim3(2, 256), 256, 0, stream>>>(y_g, t_sc, Wl3, g3, b3, gsc, bsc, stats, outp);
}

// Round 3
// 194.679 us; speedup vs baseline: 1.0973x; 1.0973x over previous
//
#include <hip/hip_runtime.h>
#include <math.h>

// B=8, N=32, M=64, D=128, OUT=128, K=3, P=N*N=1024, r=512
#define EPS 1e-5f

// stats layout (floats) in ws[0..1023]:
//  [0..127]   sum_sc   [128..255] sq_sc
//  [256..319] sum1     [320..383] sq1
//  [384..447] sum2     [448..511] sq2
//  [512..543] sum3     [544..575] sq3

__device__ __forceinline__ void fma4(float4& a, float s, const float4& v) {
    a.x += s * v.x; a.y += s * v.y; a.z += s * v.z; a.w += s * v.w;
}

// ---------------------------------------------------------------------------
// K0: materialize transposed weights in workspace.
//  Wt [64][192]: Wt[m][cc] = cc<128 ? Wsc[cc][m] : Wl1[cc-128][m]
//  Wt3[64][128]: Wt3[m][o] = Wl3[o][m]
__global__ __launch_bounds__(256) void k0_transpose(
    const float* __restrict__ Wsc, const float* __restrict__ Wl1,
    const float* __restrict__ Wl3, float* __restrict__ Wt,
    float* __restrict__ Wt3)
{
    int idx = blockIdx.x * 256 + threadIdx.x;
    if (idx < 12288) {
        int m = idx / 192, cc = idx % 192;
        Wt[idx] = (cc < 128) ? Wsc[(size_t)cc * 64 + m]
                             : Wl1[(size_t)(cc - 128) * 64 + m];
    } else if (idx < 20480) {
        int k = idx - 12288;
        int m = k >> 7, o = k & 127;
        Wt3[k] = Wl3[(size_t)o * 64 + m];
    }
}

// ---------------------------------------------------------------------------
// K1 v5: t_sc[b,o,n,d] = sum_m W_sc[o,m] x[b,n,m,d]; t_l1 likewise for W_l1.
// grid (4, 256): x = ch-group of 64 concat channels (g<3), y = (b,n).
// g==3: C1 precompute for the rank-2 FC1 collapse.
// LDS holds ONLY the swizzled x tile (36864 B -> 4 blocks/CU, 16 waves/CU).
// W fragments read directly from global Wt (L1-resident 16KB band per block).
// x rows padded to 144 floats (+16B per 32) -> 2-way banks (free).
__global__ __launch_bounds__(256, 4) void k1_matmul_stats(
    const float* __restrict__ x, const float* __restrict__ Wt,
    const float* __restrict__ Wfc1, float* __restrict__ t_sc,
    float* __restrict__ t_l1, float* __restrict__ C1,
    float* __restrict__ stats)
{
    int g  = blockIdx.x;       // 0..3
    int bn = blockIdx.y;       // 0..255
    __shared__ __align__(16) float s_x[64 * 144];   // [m][d swizzled]
    int t = threadIdx.x;

    if (g == 3) {
        // C1 precompute: block handles rows r = bn*2, bn*2+1 of W_fc1.
        //   C1[r,k] = (sum_j W1[r,k*32+j] + 2*sum_i W1[r,i*32+k] - W1[r,k*33]) / 256
#pragma unroll
        for (int rr = 0; rr < 2; rr++) {
            int r = bn * 2 + rr;
            *(float4*)(s_x + t * 4) =
                *(const float4*)(Wfc1 + (size_t)r * 1024 + t * 4);
            __syncthreads();
            if (t < 32) {
                float rs = 0.f, cs = 0.f;
#pragma unroll
                for (int j = 0; j < 32; j++) {
                    rs += s_x[t * 32 + j];      // row-block sum (S_i coeff)
                    cs += s_x[j * 32 + t];      // col sum (S_j coeff)
                }
                C1[r * 32 + t] = (rs + 2.f * cs - s_x[t * 33]) * (1.0f / 256.0f);
            }
            __syncthreads();
        }
        return;
    }

    int b = bn >> 5, n = bn & 31;
    // stage x: float4 j of row m at m*144 + j*4 + (j>>3)*4
    const float4* xg = (const float4*)(x + (size_t)bn * 8192);
    for (int i = t; i < 2048; i += 256) {
        int row = i >> 5, j = i & 31;
        *(float4*)(s_x + row * 144 + j * 4 + ((j >> 3) << 2)) = xg[i];
    }
    __syncthreads();

    int wv = t >> 6, lane = t & 63;
    int dl = lane & 15, g4 = lane >> 4;
    int d0 = dl * 8;
    int c0 = wv * 16 + g4 * 4;            // local cc base, 4 channels
    int xoff = d0 + ((dl >> 2) << 2);     // swizzled float offset
    const float* wt = Wt + g * 64 + c0;   // row stride 192

    float4 acc[4][2];
#pragma unroll
    for (int i = 0; i < 4; i++) { acc[i][0] = make_float4(0,0,0,0); acc[i][1] = make_float4(0,0,0,0); }

#pragma unroll 4
    for (int m = 0; m < 64; m += 2) {
        const float* xr = s_x + m * 144 + xoff;
        float4 x00 = *(const float4*)(xr);
        float4 x01 = *(const float4*)(xr + 4);
        float4 x10 = *(const float4*)(xr + 144);
        float4 x11 = *(const float4*)(xr + 148);
        float4 w0 = *(const float4*)(wt + m * 192);
        float4 w1 = *(const float4*)(wt + (m + 1) * 192);
        fma4(acc[0][0], w0.x, x00); fma4(acc[0][1], w0.x, x01);
        fma4(acc[1][0], w0.y, x00); fma4(acc[1][1], w0.y, x01);
        fma4(acc[2][0], w0.z, x00); fma4(acc[2][1], w0.z, x01);
        fma4(acc[3][0], w0.w, x00); fma4(acc[3][1], w0.w, x01);
        fma4(acc[0][0], w1.x, x10); fma4(acc[0][1], w1.x, x11);
        fma4(acc[1][0], w1.y, x10); fma4(acc[1][1], w1.y, x11);
        fma4(acc[2][0], w1.z, x10); fma4(acc[2][1], w1.z, x11);
        fma4(acc[3][0], w1.w, x10); fma4(acc[3][1], w1.w, x11);
    }

#pragma unroll
    for (int i = 0; i < 4; i++) {
        int cc = g * 64 + c0 + i;
        float4 v0 = acc[i][0], v1 = acc[i][1];
        float* dst;
        if (cc < 128) dst = t_sc + (((size_t)(b * 128 + cc)) * 32 + n) * 128 + d0;
        else          dst = t_l1 + (((size_t)(b * 64 + (cc - 128))) * 32 + n) * 128 + d0;
        *(float4*)dst = v0;
        *(float4*)(dst + 4) = v1;
        float s = v0.x + v0.y + v0.z + v0.w + v1.x + v1.y + v1.z + v1.w;
        float q = v0.x*v0.x + v0.y*v0.y + v0.z*v0.z + v0.w*v0.w
                + v1.x*v1.x + v1.y*v1.y + v1.z*v1.z + v1.w*v1.w;
#pragma unroll
        for (int off = 8; off > 0; off >>= 1) {
            s += __shfl_down(s, off, 16);
            q += __shfl_down(q, off, 16);
        }
        if (dl == 0) {
            if (cc < 128) {
                atomicAdd(&stats[cc], s);
                atomicAdd(&stats[cc + 128], q);
            } else {
                atomicAdd(&stats[256 + (cc - 128)], s);
                atomicAdd(&stats[320 + (cc - 128)], q);
            }
        }
    }
}

// ---------------------------------------------------------------------------
// K2: per (b,m): y = bn1(t_l1); row sums S_i; dot/eq over pairs;
// maskbits = (num>0); store y. FC1 fused via rank-2 collapse + anomalies.
// y_s rows at r*132 + (r>>2)*8 -> pair-loop b-reads are 2-way.
__device__ __forceinline__ int yb(int r) { return r * 132 + ((r >> 2) << 3); }

__global__ __launch_bounds__(256) void k2_attn_prep(
    const float* __restrict__ t_l1, const float* __restrict__ g1,
    const float* __restrict__ b1, const float* __restrict__ stats,
    const float* __restrict__ Wfc1, const float* __restrict__ C1,
    float* __restrict__ y_g, float* __restrict__ H,
    unsigned int* __restrict__ maskbits)
{
    int bm = blockIdx.x;
    int t  = threadIdx.x;
    __shared__ __align__(16) float y_s[4288];
    __shared__ float S_s[32];
    __shared__ unsigned int m_s[32];
    __shared__ int anom_cnt;
    __shared__ int anom_p[64];
    __shared__ float anom_v[64];
    int m = bm & 63;
    float mean = stats[256 + m] * (1.0f / 32768.0f);
    float var  = stats[320 + m] * (1.0f / 32768.0f) - mean * mean;
    float a = g1[m] * rsqrtf(var + EPS);
    float c = b1[m] - a * mean;

    if (t == 0) anom_cnt = 0;
    if (t < 32) m_s[t] = 0u;
    const float4* src = (const float4*)(t_l1 + (size_t)bm * 4096);
    for (int i = t; i < 1024; i += 256) {
        float4 v = src[i];
        v.x = a * v.x + c; v.y = a * v.y + c; v.z = a * v.z + c; v.w = a * v.w + c;
        int row = i >> 5, col = (i & 31) * 4;
        *(float4*)(y_s + yb(row) + col) = v;
    }
    __syncthreads();

    {   // row sums
        int r = t >> 3, j = t & 7;
        float s = 0.f;
        const float* yr = y_s + yb(r) + j * 16;
#pragma unroll
        for (int dd = 0; dd < 16; dd++) s += yr[dd];
#pragma unroll
        for (int off = 4; off > 0; off >>= 1) s += __shfl_down(s, off, 8);
        if (j == 0) S_s[r] = s;
    }
    __syncthreads();

    int i = t >> 3, j0 = (t & 7) * 4;
    float dot[4] = {0.f, 0.f, 0.f, 0.f};
    float eqs[4] = {0.f, 0.f, 0.f, 0.f};
    const float* yi = y_s + yb(i);
    const float* yj[4] = { y_s + yb(j0), y_s + yb(j0 + 1),
                           y_s + yb(j0 + 2), y_s + yb(j0 + 3) };
    for (int dq = 0; dq < 32; dq++) {
        float4 a4 = *(const float4*)(yi + dq * 4);
#pragma unroll
        for (int q = 0; q < 4; q++) {
            float4 b4 = *(const float4*)(yj[q] + dq * 4);
            dot[q] += a4.x * b4.x + a4.y * b4.y + a4.z * b4.z + a4.w * b4.w;
            eqs[q] += (a4.x == b4.x ? b4.x : 0.f) + (a4.y == b4.y ? b4.y : 0.f)
                    + (a4.z == b4.z ? b4.z : 0.f) + (a4.w == b4.w ? b4.w : 0.f);
        }
    }
    float Si = S_s[i];
    unsigned int bits = 0u;
#pragma unroll
    for (int q = 0; q < 4; q++) {
        int j = j0 + q;
        float Sj = S_s[j];
        float num = dot[q] - Si * Sj * (1.0f / 128.0f);
        if (num > 0.f) bits |= (1u << j);
        // exact-collision correction term for the FC1 collapse (diag is in C1)
        if (j != i && eqs[q] != 0.f) {
            int idx = atomicAdd(&anom_cnt, 1);
            if (idx < 64) {
                anom_p[idx] = i * 32 + j;
                anom_v[idx] = eqs[q] * (1.0f / 256.0f);
            }
        }
    }
    atomicOr(&m_s[i], bits);
    __syncthreads();
    if (t < 32) maskbits[bm * 32 + t] = m_s[t];

    // fused FC1: h[bm, r] = relu( sum_k C1[r,k]*S_k - sum_anom W1[r,p]*v )
    int cnt = anom_cnt; if (cnt > 64) cnt = 64;
#pragma unroll
    for (int rr = 0; rr < 2; rr++) {
        int r = t * 2 + rr;
        const float4* c1r = (const float4*)(C1 + r * 32);
        float acc = 0.f;
#pragma unroll
        for (int kk = 0; kk < 8; kk++) {
            float4 cv = c1r[kk];
            acc += cv.x * S_s[kk * 4 + 0] + cv.y * S_s[kk * 4 + 1]
                 + cv.z * S_s[kk * 4 + 2] + cv.w * S_s[kk * 4 + 3];
        }
        for (int a2 = 0; a2 < cnt; a2++)
            acc -= Wfc1[(size_t)r * 1024 + anom_p[a2]] * anom_v[a2];
        H[(size_t)bm * 512 + r] = fmaxf(acc, 0.f);
    }

    float4* yd = (float4*)(y_g + (size_t)bm * 4096);
    for (int idx = t; idx < 1024; idx += 256) {
        int row = idx >> 5, col = (idx & 31) * 4;
        yd[idx] = *(const float4*)(y_s + yb(row) + col);
    }
}

// ---------------------------------------------------------------------------
// K3: C[r,c] = epi( sum_k A[r,k] * Bm[c,k] ). 32x32 tile per block,
// in-block split-K: 4 waves, each owns K/4 via wave-private LDS slabs.
// MODE 1: sigmoid (FC2). (FC1 is collapsed into K2.)
template<int KDIM, int MODE>
__global__ __launch_bounds__(256) void k3_gemm(
    const float* __restrict__ A, const float* __restrict__ Bm,
    float* __restrict__ C, int NC)
{
    __shared__ __align__(16) float lds[4 * 2304];   // per wave: As 32x36, Bs 32x36
    int t = threadIdx.x;
    int w = t >> 6, l = t & 63;
    int ct = blockIdx.x, rt = blockIdx.y;
    int row0 = rt * 32, col0 = ct * 32;
    float* As = lds + w * 2304;
    float* Bs = As + 1152;
    int rg = l >> 3;           // 0..7 : rows rg*4.., also staging row group
    int cg = l & 7;            // 0..7 : cols cg*4..
    int kq = (l & 7) * 4;      // staging k-offset within slab
    constexpr int SLABS = KDIM / 128;

    float4 acc[4];
#pragma unroll
    for (int ii = 0; ii < 4; ii++) acc[ii] = make_float4(0,0,0,0);

    float4 av[4], bv[4], av2[4], bv2[4];
    int k0 = w * 32;
#pragma unroll
    for (int rr = 0; rr < 4; rr++) {
        int r = rg + rr * 8;
        av[rr] = *(const float4*)(A  + (size_t)(row0 + r) * KDIM + k0 + kq);
        bv[rr] = *(const float4*)(Bm + (size_t)(col0 + r) * KDIM + k0 + kq);
    }

    for (int s = 0; s < SLABS; s++) {
#pragma unroll
        for (int rr = 0; rr < 4; rr++) {
            int r = rg + rr * 8;
            As[(kq + 0) * 36 + r] = av[rr].x; As[(kq + 1) * 36 + r] = av[rr].y;
            As[(kq + 2) * 36 + r] = av[rr].z; As[(kq + 3) * 36 + r] = av[rr].w;
            Bs[(kq + 0) * 36 + r] = bv[rr].x; Bs[(kq + 1) * 36 + r] = bv[rr].y;
            Bs[(kq + 2) * 36 + r] = bv[rr].z; Bs[(kq + 3) * 36 + r] = bv[rr].w;
        }
        if (s + 1 < SLABS) {
            int kn = (4 * (s + 1) + w) * 32;
#pragma unroll
            for (int rr = 0; rr < 4; rr++) {
                int r = rg + rr * 8;
                av2[rr] = *(const float4*)(A  + (size_t)(row0 + r) * KDIM + kn + kq);
                bv2[rr] = *(const float4*)(Bm + (size_t)(col0 + r) * KDIM + kn + kq);
            }
        }
#pragma unroll
        for (int k = 0; k < 32; k++) {
            float4 a = *(const float4*)(As + k * 36 + rg * 4);
            float4 b = *(const float4*)(Bs + k * 36 + cg * 4);
            fma4(acc[0], a.x, b);
            fma4(acc[1], a.y, b);
            fma4(acc[2], a.z, b);
            fma4(acc[3], a.w, b);
        }
#pragma unroll
        for (int rr = 0; rr < 4; rr++) { av[rr] = av2[rr]; bv[rr] = bv2[rr]; }
    }

    __syncthreads();
    float* red = lds;          // 4 x 1024 overlay
#pragma unroll
    for (int ii = 0; ii < 4; ii++)
        *(float4*)(red + w * 1024 + (rg * 4 + ii) * 32 + cg * 4) = acc[ii];
    __syncthreads();

    int r = t >> 3, c4 = (t & 7) * 4;
    float4 s0 = *(const float4*)(red + r * 32 + c4);
    float4 s1 = *(const float4*)(red + 1024 + r * 32 + c4);
    float4 s2 = *(const float4*)(red + 2048 + r * 32 + c4);
    float4 s3 = *(const float4*)(red + 3072 + r * 32 + c4);
    float4 v;
    v.x = s0.x + s1.x + s2.x + s3.x;
    v.y = s0.y + s1.y + s2.y + s3.y;
    v.z = s0.z + s1.z + s2.z + s3.z;
    v.w = s0.w + s1.w + s2.w + s3.w;
    if (MODE == 0) {
        v.x = fmaxf(v.x, 0.f); v.y = fmaxf(v.y, 0.f);
        v.z = fmaxf(v.z, 0.f); v.w = fmaxf(v.w, 0.f);
    } else {
        v.x = 1.0f / (1.0f + expf(-v.x)); v.y = 1.0f / (1.0f + expf(-v.y));
        v.z = 1.0f / (1.0f + expf(-v.z)); v.w = 1.0f / (1.0f + expf(-v.w));
    }
    *(float4*)(C + (size_t)(row0 + r) * NC + col0 + c4) = v;
}

// ---------------------------------------------------------------------------
// K4: per (b,m): att = softmax_j( mask ? e2 : -1e12 ); out = att @ y; stats2.
// j-outer MV loop: each y[j] float4 read once.
__global__ __launch_bounds__(256) void k4_attn_apply(
    const float* __restrict__ E2, const unsigned int* __restrict__ maskbits,
    const float* __restrict__ y_g, float* __restrict__ att_out,
    float* __restrict__ stats)
{
    int bm = blockIdx.x;
    int t  = threadIdx.x;
    __shared__ __align__(16) float att_s[32 * 33];
    __shared__ __align__(16) float y_sh[32 * 128];
    __shared__ float redS[4], redQ[4];

    const float4* ysrc = (const float4*)(y_g + (size_t)bm * 4096);
    float4* yds = (float4*)y_sh;
    for (int i = t; i < 1024; i += 256) yds[i] = ysrc[i];

    {
        int r = t >> 3, j0 = (t & 7) * 4;
        unsigned int mk = maskbits[bm * 32 + r];
        float4 e4 = *(const float4*)(E2 + (size_t)bm * 1024 + r * 32 + j0);
        float v0 = ((mk >> (j0 + 0)) & 1u) ? e4.x : -1e12f;
        float v1 = ((mk >> (j0 + 1)) & 1u) ? e4.y : -1e12f;
        float v2 = ((mk >> (j0 + 2)) & 1u) ? e4.z : -1e12f;
        float v3 = ((mk >> (j0 + 3)) & 1u) ? e4.w : -1e12f;
        float mx = fmaxf(fmaxf(v0, v1), fmaxf(v2, v3));
#pragma unroll
        for (int off = 1; off < 8; off <<= 1) mx = fmaxf(mx, __shfl_xor(mx, off, 8));
        float e0 = __expf(v0 - mx), e1 = __expf(v1 - mx);
        float e2 = __expf(v2 - mx), e3 = __expf(v3 - mx);
        float s = e0 + e1 + e2 + e3;
#pragma unroll
        for (int off = 1; off < 8; off <<= 1) s += __shfl_xor(s, off, 8);
        float inv = 1.0f / s;
        att_s[r * 33 + j0 + 0] = e0 * inv;
        att_s[r * 33 + j0 + 1] = e1 * inv;
        att_s[r * 33 + j0 + 2] = e2 * inv;
        att_s[r * 33 + j0 + 3] = e3 * inv;
    }
    __syncthreads();

    int tx = t & 31, ty = t >> 5;
    int dq = tx * 4;
    int i0 = ty * 4;
    float4 acc0 = make_float4(0,0,0,0), acc1 = make_float4(0,0,0,0);
    float4 acc2 = make_float4(0,0,0,0), acc3 = make_float4(0,0,0,0);
    for (int j = 0; j < 32; j++) {
        float4 yv = *(const float4*)(y_sh + j * 128 + dq);
        float w0 = att_s[(i0 + 0) * 33 + j];
        float w1 = att_s[(i0 + 1) * 33 + j];
        float w2 = att_s[(i0 + 2) * 33 + j];
        float w3 = att_s[(i0 + 3) * 33 + j];
        fma4(acc0, w0, yv);
        fma4(acc1, w1, yv);
        fma4(acc2, w2, yv);
        fma4(acc3, w3, yv);
    }
    float ssum = 0.f, sq = 0.f;
    float4 accs[4] = {acc0, acc1, acc2, acc3};
#pragma unroll
    for (int ii = 0; ii < 4; ii++) {
        float4 acc = accs[ii];
        *(float4*)(att_out + (size_t)bm * 4096 + (i0 + ii) * 128 + dq) = acc;
        ssum += acc.x + acc.y + acc.z + acc.w;
        sq   += acc.x * acc.x + acc.y * acc.y + acc.z * acc.z + acc.w * acc.w;
    }
#pragma unroll
    for (int off = 32; off > 0; off >>= 1) {
        ssum += __shfl_down(ssum, off, 64);
        sq   += __shfl_down(sq, off, 64);
    }
    int wave = t >> 6, lane = t & 63;
    if (lane == 0) { redS[wave] = ssum; redQ[wave] = sq; }
    __syncthreads();
    if (t == 0) {
        float S = redS[0] + redS[1] + redS[2] + redS[3];
        float Q = redQ[0] + redQ[1] + redQ[2] + redQ[3];
        int m = bm & 63;
        atomicAdd(&stats[384 + m], S);
        atomicAdd(&stats[448 + m], Q);
    }
}

// ---------------------------------------------------------------------------
// K5: per (b,n): z = relu(bn2(att_out)); 3x3 depthwise conv; stats3.
__global__ __launch_bounds__(256) void k5_conv(
    const float* __restrict__ att_out, const float* __restrict__ Wdw,
    const float* __restrict__ g2, const float* __restrict__ b2,
    float* __restrict__ stats, float* __restrict__ v_g)
{
    int bn = blockIdx.x;
    int b = bn >> 5, n = bn & 31;
    int t = threadIdx.x;
    __shared__ __align__(16) float z_s[66 * 130];
    __shared__ float a2_s[64], c2_s[64];
    __shared__ float redS[4], redQ[4];

    if (t < 64) {
        float mean = stats[384 + t] * (1.0f / 32768.0f);
        float var  = stats[448 + t] * (1.0f / 32768.0f) - mean * mean;
        float a = g2[t] * rsqrtf(var + EPS);
        a2_s[t] = a; c2_s[t] = b2[t] - a * mean;
    }
    for (int i = t; i < 66 * 130; i += 256) z_s[i] = 0.f;
    __syncthreads();

    for (int i = t; i < 2048; i += 256) {
        int m = i >> 5, c4 = (i & 31) * 4;
        float4 vv = *(const float4*)(att_out + (((size_t)(b * 64 + m)) * 32 + n) * 128 + c4);
        float a = a2_s[m], c = c2_s[m];
        float* dst = z_s + (m + 1) * 130 + c4 + 1;
        dst[0] = fmaxf(a * vv.x + c, 0.f);
        dst[1] = fmaxf(a * vv.y + c, 0.f);
        dst[2] = fmaxf(a * vv.z + c, 0.f);
        dst[3] = fmaxf(a * vv.w + c, 0.f);
    }
    float w[9];
#pragma unroll
    for (int i = 0; i < 9; i++) w[i] = Wdw[n * 9 + i];
    __syncthreads();

    int tx = t & 31, ty = t >> 5;
    int d0 = tx * 4;
    float ssum = 0.f, sq = 0.f;
#pragma unroll
    for (int rr = 0; rr < 8; rr++) {
        int h = ty * 8 + rr;
        float o0 = 0.f, o1 = 0.f, o2 = 0.f, o3 = 0.f;
#pragma unroll
        for (int dh = 0; dh < 3; dh++) {
            const float* zr = z_s + (h + dh) * 130 + d0;
#pragma unroll
            for (int dw = 0; dw < 3; dw++) {
                float wv = w[dh * 3 + dw];
                o0 += wv * zr[dw + 0];
                o1 += wv * zr[dw + 1];
                o2 += wv * zr[dw + 2];
                o3 += wv * zr[dw + 3];
            }
        }
        *(float4*)(v_g + ((size_t)bn * 64 + h) * 128 + d0) = make_float4(o0, o1, o2, o3);
        ssum += o0 + o1 + o2 + o3;
        sq   += o0 * o0 + o1 * o1 + o2 * o2 + o3 * o3;
    }
#pragma unroll
    for (int off = 32; off > 0; off >>= 1) {
        ssum += __shfl_down(ssum, off, 64);
        sq   += __shfl_down(sq, off, 64);
    }
    int wave = t >> 6, lane = t & 63;
    if (lane == 0) { redS[wave] = ssum; redQ[wave] = sq; }
    __syncthreads();
    if (t == 0) {
        atomicAdd(&stats[512 + n], redS[0] + redS[1] + redS[2] + redS[3]);
        atomicAdd(&stats[544 + n], redQ[0] + redQ[1] + redQ[2] + redQ[3]);
    }
}

// ---------------------------------------------------------------------------
// K6 v4: out[b,n,o,d] = sum_m Wl3[o,m]*relu(bn3(v[b,n,m,d])) + bn_sc(t_sc)
// grid (2, 256): x = o-half of 64, y = (b,n). Same core as K1 v5:
// LDS = swizzled z tile only (36864 B, 4 blocks/CU); Wt3 read from global.
__global__ __launch_bounds__(256, 4) void k6_final(
    const float* __restrict__ v_g, const float* __restrict__ t_sc,
    const float* __restrict__ Wt3, const float* __restrict__ g3,
    const float* __restrict__ b3, const float* __restrict__ gsc,
    const float* __restrict__ bsc, const float* __restrict__ stats,
    float* __restrict__ outp)
{
    int oh = blockIdx.x;       // 0/1
    int bn = blockIdx.y;
    int b = bn >> 5, n = bn & 31;
    int t = threadIdx.x;
    __shared__ __align__(16) float z_s[64 * 144];   // [m][d swizzled] relu(bn3(v))

    float mean3 = stats[512 + n] * (1.0f / 65536.0f);
    float var3  = stats[544 + n] * (1.0f / 65536.0f) - mean3 * mean3;
    float a3 = g3[n] * rsqrtf(var3 + EPS);
    float c3 = b3[n] - a3 * mean3;

    const float4* vsrc = (const float4*)(v_g + (size_t)bn * 8192);
    for (int i = t; i < 2048; i += 256) {
        float4 vv = vsrc[i];
        float4 r;
        r.x = fmaxf(a3 * vv.x + c3, 0.f);
        r.y = fmaxf(a3 * vv.y + c3, 0.f);
        r.z = fmaxf(a3 * vv.z + c3, 0.f);
        r.w = fmaxf(a3 * vv.w + c3, 0.f);
        int row = i >> 5, j = i & 31;
        *(float4*)(z_s + row * 144 + j * 4 + ((j >> 3) << 2)) = r;
    }
    __syncthreads();

    int wv = t >> 6, lane = t & 63;
    int dl = lane & 15, g4 = lane >> 4;
    int d0 = dl * 8;
    int c0 = wv * 16 + g4 * 4;
    int xoff = d0 + ((dl >> 2) << 2);
    const float* wt = Wt3 + oh * 64 + c0;   // row stride 128

    float4 acc[4][2];
#pragma unroll
    for (int i = 0; i < 4; i++) { acc[i][0] = make_float4(0,0,0,0); acc[i][1] = make_float4(0,0,0,0); }

#pragma unroll 4
    for (int m = 0; m < 64; m += 2) {
        const float* xr = z_s + m * 144 + xoff;
        float4 x00 = *(const float4*)(xr);
        float4 x01 = *(const float4*)(xr + 4);
        float4 x10 = *(const float4*)(xr + 144);
        float4 x11 = *(const float4*)(xr + 148);
        float4 w0 = *(const float4*)(wt + m * 128);
        float4 w1 = *(const float4*)(wt + (m + 1) * 128);
        fma4(acc[0][0], w0.x, x00); fma4(acc[0][1], w0.x, x01);
        fma4(acc[1][0], w0.y, x00); fma4(acc[1][1], w0.y, x01);
        fma4(acc[2][0], w0.z, x00); fma4(acc[2][1], w0.z, x01);
        fma4(acc[3][0], w0.w, x00); fma4(acc[3][1], w0.w, x01);
        fma4(acc[0][0], w1.x, x10); fma4(acc[0][1], w1.x, x11);
        fma4(acc[1][0], w1.y, x10); fma4(acc[1][1], w1.y, x11);
        fma4(acc[2][0], w1.z, x10); fma4(acc[2][1], w1.z, x11);
        fma4(acc[3][0], w1.w, x10); fma4(acc[3][1], w1.w, x11);
    }

#pragma unroll
    for (int i = 0; i < 4; i++) {
        int o = oh * 64 + c0 + i;
        float msc = stats[o] * (1.0f / 32768.0f);
        float vsc = stats[128 + o] * (1.0f / 32768.0f) - msc * msc;
        float asc = gsc[o] * rsqrtf(vsc + EPS);
        float csc = bsc[o] - asc * msc;
        const float* ts = t_sc + (((size_t)(b * 128 + o)) * 32 + n) * 128 + d0;
        float4 t0 = *(const float4*)(ts);
        float4 t1 = *(const float4*)(ts + 4);
        float4 o0 = acc[i][0], o1 = acc[i][1];
        o0.x += asc * t0.x + csc; o0.y += asc * t0.y + csc;
        o0.z += asc * t0.z + csc; o0.w += asc * t0.w + csc;
        o1.x += asc * t1.x + csc; o1.y += asc * t1.y + csc;
        o1.z += asc * t1.z + csc; o1.w += asc * t1.w + csc;
        float* dst = outp + (((size_t)(b * 32 + n)) * 128 + o) * 128 + d0;
        *(float4*)dst = o0;
        *(float4*)(dst + 4) = o1;
    }
}

// ---------------------------------------------------------------------------
extern "C" void kernel_launch(void* const* d_in, const int* in_sizes, int n_in,
                              void* d_out, int out_size, void* d_ws, size_t ws_size,
                              hipStream_t stream)
{
    const float* x    = (const float*)d_in[0];
    const float* Wsc  = (const float*)d_in[1];
    const float* gsc  = (const float*)d_in[2];
    const float* bsc  = (const float*)d_in[3];
    const float* Wl1  = (const float*)d_in[4];
    const float* g1   = (const float*)d_in[5];
    const float* b1   = (const float*)d_in[6];
    const float* Wfc1 = (const float*)d_in[7];
    const float* Wfc2 = (const float*)d_in[8];
    const float* g2   = (const float*)d_in[9];
    const float* b2   = (const float*)d_in[10];
    const float* Wdw  = (const float*)d_in[11];
    const float* g3   = (const float*)d_in[12];
    const float* b3   = (const float*)d_in[13];
    const float* Wl3  = (const float*)d_in[14];
    float* outp = (float*)d_out;

    float* ws = (float*)d_ws;
    float* stats = ws;                          // 1024
    float* t_sc  = ws + 1024;                   // 4194304
    float* t_l1  = t_sc + 4194304;              // 2097152 (reused as att_out)
    float* y_g   = t_l1 + 2097152;              // 2097152 (reused as conv out)
    float* C1    = y_g + 2097152;               // 16384 (FC1 collapse matrix)
    float* H     = C1 + 16384;                  // 262144
    float* E2    = H + 262144;                  // 524288
    unsigned int* maskb = (unsigned int*)(E2 + 524288);  // 16384 u32
    float* Wt    = (float*)(maskb + 16384);     // 12288 (W_sc|W_l1 transposed)
    float* Wt3   = Wt + 12288;                  // 8192  (W_l3 transposed)

    (void)hipMemsetAsync(stats, 0, 1024 * sizeof(float), stream);

    k0_transpose<<<80, 256, 0, stream>>>(Wsc, Wl1, Wl3, Wt, Wt3);
    k1_matmul_stats<<<dim3(4, 256), 256, 0, stream>>>(x, Wt, Wfc1, t_sc, t_l1, C1, stats);
    k2_attn_prep<<<512, 256, 0, stream>>>(t_l1, g1, b1, stats, Wfc1, C1, y_g, H, maskb);
    k3_gemm<512, 1><<<dim3(32, 16), 256, 0, stream>>>(H, Wfc2, E2, 1024);
    k4_attn_apply<<<512, 256, 0, stream>>>(E2, maskb, y_g, t_l1, stats);
    k5_conv<<<256, 256, 0, stream>>>(t_l1, Wdw, g2, b2, stats, y_g);
    k6_final<<<dim3(2, 256), 256, 0, stream>>>(y_g, t_sc, Wt3, g3, b3, gsc, bsc, stats, outp);
}